// Round 3
// baseline (628.292 us; speedup 1.0000x reference)
//
#include <hip/hip_runtime.h>
#include <math.h>

// Problem constants
#define BB 16
#define CC 64
#define HH 160
#define WW 160
#define KK 8
#define OO 64
#define AA 16
#define HWQ (HH * WW)          // 25600
#define CCHUNK 8               // channels staged per iteration

// ---------------------------------------------------------------------------
// Kernel A: global average pool per (b,c): gap[b*C+c] = mean(x[b,c,:,:])
// ---------------------------------------------------------------------------
__global__ __launch_bounds__(256) void gap_kernel(const float* __restrict__ x,
                                                  float* __restrict__ gap) {
    int bc = blockIdx.x;  // 0..1023
    const float4* p = (const float4*)(x + (size_t)bc * HWQ);
    float s = 0.f;
    for (int i = threadIdx.x; i < HWQ / 4; i += 256) {
        float4 v = p[i];
        s += v.x + v.y + v.z + v.w;
    }
    // wave64 reduce
    for (int off = 32; off > 0; off >>= 1) s += __shfl_down(s, off, 64);
    __shared__ float red[4];
    if ((threadIdx.x & 63) == 0) red[threadIdx.x >> 6] = s;
    __syncthreads();
    if (threadIdx.x == 0) {
        float t = red[0] + red[1] + red[2] + red[3];
        gap[bc] = t / (float)HWQ;
    }
}

// ---------------------------------------------------------------------------
// Kernel B: routing MLP + BN + 4 attention heads. One block per batch sample.
// ---------------------------------------------------------------------------
__global__ __launch_bounds__(128) void mlp_kernel(
    const float* __restrict__ scale,
    const float* __restrict__ rw1, const float* __restrict__ rb1,
    const float* __restrict__ rw2, const float* __restrict__ rb2,
    const float* __restrict__ fc_w,
    const float* __restrict__ bn_gamma, const float* __restrict__ bn_beta,
    const float* __restrict__ bn_mean, const float* __restrict__ bn_var,
    const float* __restrict__ cfc_w, const float* __restrict__ cfc_b,
    const float* __restrict__ ffc_w, const float* __restrict__ ffc_b,
    const float* __restrict__ sfc_w, const float* __restrict__ sfc_b,
    const float* __restrict__ kfc_w, const float* __restrict__ kfc_b,
    const float* __restrict__ gap,
    float* __restrict__ ca, float* __restrict__ fa,
    float* __restrict__ sa, float* __restrict__ ka) {
    int b = blockIdx.x;
    int t = threadIdx.x;
    __shared__ float sin_[CC + 2];
    __shared__ float h1[2 * CC];
    __shared__ float h2[CC];
    __shared__ float vv[AA];
    __shared__ float kl[KK];

    if (t < 2) sin_[t] = 1.0f / scale[t];
    else if (t < CC + 2) sin_[t] = gap[b * CC + (t - 2)];
    __syncthreads();

    // layer 1: [2C] = relu(s @ rw1.T + rb1), rw1: [2C, C+2]
    {
        float a = rb1[t];
        const float* wr = rw1 + (size_t)t * (CC + 2);
        #pragma unroll 6
        for (int j = 0; j < CC + 2; ++j) a += sin_[j] * wr[j];
        h1[t] = fmaxf(a, 0.f);
    }
    __syncthreads();

    // layer 2: [C] = relu(h1 @ rw2.T + rb2), rw2: [C, 2C]
    if (t < CC) {
        float a = rb2[t];
        const float* wr = rw2 + (size_t)t * (2 * CC);
        #pragma unroll 8
        for (int j = 0; j < 2 * CC; ++j) a += h1[j] * wr[j];
        h2[t] = fmaxf(a, 0.f);
    }
    __syncthreads();

    // v: [A] = relu(BN(h2 @ fc_w.T)), fc_w: [A, C]
    if (t < AA) {
        float a = 0.f;
        const float* wr = fc_w + (size_t)t * CC;
        #pragma unroll 8
        for (int j = 0; j < CC; ++j) a += h2[j] * wr[j];
        a = (a - bn_mean[t]) * rsqrtf(bn_var[t] + 1e-5f) * bn_gamma[t] + bn_beta[t];
        vv[t] = fmaxf(a, 0.f);
    }
    __syncthreads();

    // channel / filter attentions (sigmoid)
    if (t < CC) {
        float a = cfc_b[t];
        const float* wr = cfc_w + (size_t)t * AA;
        #pragma unroll
        for (int j = 0; j < AA; ++j) a += vv[j] * wr[j];
        ca[b * CC + t] = 1.f / (1.f + expf(-a));
        float f = ffc_b[t];
        const float* wf = ffc_w + (size_t)t * AA;
        #pragma unroll
        for (int j = 0; j < AA; ++j) f += vv[j] * wf[j];
        fa[b * CC + t] = 1.f / (1.f + expf(-f));
    }
    // spatial attention (sigmoid), stored with stride 16
    if (t < 9) {
        float a = sfc_b[t];
        const float* wr = sfc_w + (size_t)t * AA;
        #pragma unroll
        for (int j = 0; j < AA; ++j) a += vv[j] * wr[j];
        sa[b * 16 + t] = 1.f / (1.f + expf(-a));
    }
    // kernel attention logits
    if (t < KK) {
        float a = kfc_b[t];
        const float* wr = kfc_w + (size_t)t * AA;
        #pragma unroll
        for (int j = 0; j < AA; ++j) a += vv[j] * wr[j];
        kl[t] = a;
    }
    __syncthreads();
    // softmax over 8 (redundant per-thread, trivial)
    if (t < KK) {
        float m = kl[0];
        #pragma unroll
        for (int j = 1; j < KK; ++j) m = fmaxf(m, kl[j]);
        float sum = 0.f;
        #pragma unroll
        for (int j = 0; j < KK; ++j) sum += expf(kl[j] - m);
        ka[b * KK + t] = expf(kl[t] - m) / sum;
    }
}

// ---------------------------------------------------------------------------
// Kernel C: aggregate expert weights, folding channel/filter/spatial atts:
//   W2[b][c][q][o] = fa[b,o]*ca[b,c]*sa[b,q] * sum_k ka[b,k]*weight[k,o,c,q]
// Thread index maps to (b,o,cq) with cq fastest -> coalesced weight reads.
// ---------------------------------------------------------------------------
__global__ __launch_bounds__(256) void agg_kernel(
    const float* __restrict__ weight,
    const float* __restrict__ ca, const float* __restrict__ fa,
    const float* __restrict__ sa, const float* __restrict__ ka,
    float* __restrict__ W2) {
    int idx = blockIdx.x * 256 + threadIdx.x;  // < 16*64*576 = 589824
    int cq = idx % 576;
    int bo = idx / 576;
    int o = bo & 63;
    int b = bo >> 6;
    int c = cq / 9;
    int q = cq - c * 9;
    float s = 0.f;
    #pragma unroll
    for (int k = 0; k < KK; ++k)
        s += ka[b * KK + k] * weight[(size_t)(k * OO + o) * 576 + cq];
    W2[(((size_t)b * CC + c) * 9 + q) * OO + o] =
        s * sa[b * 16 + q] * ca[b * CC + c] * fa[b * CC + o];
}

// ---------------------------------------------------------------------------
// Kernel D: per-sample 3x3 conv, pad 1. Block: 16x16 spatial x 64 o-channels.
// Thread: 8 o x 8 consecutive w positions (register tile), c staged in
// chunks of 8 through LDS together with the per-(b,c-chunk) weights.
// ---------------------------------------------------------------------------
__global__ __launch_bounds__(256) void conv_kernel(
    const float* __restrict__ x, const float* __restrict__ W2,
    float* __restrict__ out) {
    __shared__ float xs[CCHUNK][18][20];    // 11.5 KB, row stride 20 (16B-aligned)
    __shared__ float wsm[CCHUNK][9][OO];    // 18.4 KB

    const int b = blockIdx.z;
    const int h0 = blockIdx.y * 16;
    const int w0 = blockIdx.x * 16;
    const int tid = threadIdx.x;
    const int og = tid >> 5;          // 0..7 -> o base = og*8
    const int sg = tid & 31;          // 0..31
    const int r = sg >> 1;            // row 0..15 within tile
    const int colb = (sg & 1) * 8;    // col base 0 or 8

    const float* xb = x + (size_t)b * CC * HWQ;
    const float* wb = W2 + (size_t)b * CC * 9 * OO;

    float acc[8][8];
    #pragma unroll
    for (int i = 0; i < 8; ++i)
        #pragma unroll
        for (int j = 0; j < 8; ++j) acc[i][j] = 0.f;

    for (int cc = 0; cc < CC; cc += CCHUNK) {
        // stage x halo tile: CCHUNK * 18 * 18 = 2592 elements
        for (int i = tid; i < CCHUNK * 18 * 18; i += 256) {
            int c = i / 324;
            int rem = i - c * 324;
            int hh = rem / 18;
            int ww = rem - hh * 18;
            int gh = h0 + hh - 1;
            int gw = w0 + ww - 1;
            float v = 0.f;
            if ((unsigned)gh < (unsigned)HH && (unsigned)gw < (unsigned)WW)
                v = xb[(size_t)(cc + c) * HWQ + gh * WW + gw];
            xs[c][hh][ww] = v;
        }
        // stage weights: contiguous CCHUNK*9*64 floats
        {
            const float4* wsrc = (const float4*)(wb + (size_t)cc * 9 * OO);
            float4* wdst = (float4*)(&wsm[0][0][0]);
            for (int i = tid; i < CCHUNK * 9 * OO / 4; i += 256)
                wdst[i] = wsrc[i];
        }
        __syncthreads();

        #pragma unroll 2
        for (int c = 0; c < CCHUNK; ++c) {
            #pragma unroll
            for (int kh = 0; kh < 3; ++kh) {
                const float* xrow = &xs[c][r + kh][colb];
                float4 a0 = *(const float4*)(xrow);
                float4 a1 = *(const float4*)(xrow + 4);
                float2 a2 = *(const float2*)(xrow + 8);
                float xv[10] = {a0.x, a0.y, a0.z, a0.w,
                                a1.x, a1.y, a1.z, a1.w,
                                a2.x, a2.y};
                #pragma unroll
                for (int kw = 0; kw < 3; ++kw) {
                    const float* wrow = &wsm[c][kh * 3 + kw][og * 8];
                    float4 b0 = *(const float4*)(wrow);
                    float4 b1 = *(const float4*)(wrow + 4);
                    float wv[8] = {b0.x, b0.y, b0.z, b0.w,
                                   b1.x, b1.y, b1.z, b1.w};
                    #pragma unroll
                    for (int i = 0; i < 8; ++i)
                        #pragma unroll
                        for (int j = 0; j < 8; ++j)
                            acc[i][j] += wv[i] * xv[kw + j];
                }
            }
        }
        __syncthreads();
    }

    // epilogue: filter_att and channel_att already folded into W2
    #pragma unroll
    for (int i = 0; i < 8; ++i) {
        float* orow = out + (((size_t)b * OO + og * 8 + i) * HH + (h0 + r)) * WW
                      + w0 + colb;
        float4 o0 = {acc[i][0], acc[i][1], acc[i][2], acc[i][3]};
        float4 o1 = {acc[i][4], acc[i][5], acc[i][6], acc[i][7]};
        *(float4*)(orow) = o0;
        *(float4*)(orow + 4) = o1;
    }
}

// ---------------------------------------------------------------------------
extern "C" void kernel_launch(void* const* d_in, const int* in_sizes, int n_in,
                              void* d_out, int out_size, void* d_ws, size_t ws_size,
                              hipStream_t stream) {
    const float* x        = (const float*)d_in[0];
    const float* scale    = (const float*)d_in[1];
    const float* rw1      = (const float*)d_in[2];
    const float* rb1      = (const float*)d_in[3];
    const float* rw2      = (const float*)d_in[4];
    const float* rb2      = (const float*)d_in[5];
    const float* fc_w     = (const float*)d_in[6];
    const float* bn_gamma = (const float*)d_in[7];
    const float* bn_beta  = (const float*)d_in[8];
    const float* bn_mean  = (const float*)d_in[9];
    const float* bn_var   = (const float*)d_in[10];
    const float* cfc_w    = (const float*)d_in[11];
    const float* cfc_b    = (const float*)d_in[12];
    const float* ffc_w    = (const float*)d_in[13];
    const float* ffc_b    = (const float*)d_in[14];
    const float* sfc_w    = (const float*)d_in[15];
    const float* sfc_b    = (const float*)d_in[16];
    const float* kfc_w    = (const float*)d_in[17];
    const float* kfc_b    = (const float*)d_in[18];
    const float* weight   = (const float*)d_in[19];

    float* ws  = (float*)d_ws;
    float* gap = ws;              // 1024
    float* ca  = ws + 1024;       // 1024
    float* fa  = ws + 2048;       // 1024
    float* sa  = ws + 3072;       // 256 (stride 16 per b)
    float* ka  = ws + 3328;       // 128
    float* W2  = ws + 4096;       // 589824

    gap_kernel<<<dim3(BB * CC), dim3(256), 0, stream>>>(x, gap);
    mlp_kernel<<<dim3(BB), dim3(128), 0, stream>>>(
        scale, rw1, rb1, rw2, rb2, fc_w, bn_gamma, bn_beta, bn_mean, bn_var,
        cfc_w, cfc_b, ffc_w, ffc_b, sfc_w, sfc_b, kfc_w, kfc_b,
        gap, ca, fa, sa, ka);
    agg_kernel<<<dim3(589824 / 256), dim3(256), 0, stream>>>(weight, ca, fa, sa, ka, W2);
    conv_kernel<<<dim3(10, 10, BB), dim3(256), 0, stream>>>(x, W2, (float*)d_out);
}

// Round 5
// 402.743 us; speedup vs baseline: 1.5600x; 1.5600x over previous
//
#include <hip/hip_runtime.h>
#include <math.h>

// Problem constants
#define BB 16
#define CC 64
#define HH 160
#define WW 160
#define KK 8
#define OO 64
#define AA 16
#define HWQ (HH * WW)          // 25600

typedef __attribute__((ext_vector_type(8))) short sh8;
typedef __attribute__((ext_vector_type(4))) float fx4;

__device__ inline unsigned short f2bf(float f) {
    unsigned int u = __float_as_uint(f);
    return (unsigned short)((u + 0x7FFFu + ((u >> 16) & 1u)) >> 16);
}
__device__ inline float bf2f(unsigned short h) {
    return __uint_as_float(((unsigned int)h) << 16);
}

// ---------------------------------------------------------------------------
// Kernel A: transpose x [b][c][h][w] fp32 -> xt_hi/xt_lo [b][h][w][c] bf16
// (split precision: x = hi + lo), fused with GAP partial sums (atomicAdd).
// One block per (b, h, 32-wide w tile).
// ---------------------------------------------------------------------------
__global__ __launch_bounds__(256) void trans_gap_kernel(
    const float* __restrict__ x,
    unsigned short* __restrict__ xt_hi, unsigned short* __restrict__ xt_lo,
    float* __restrict__ gap) {
    __shared__ float ts[64][33];
    const int w0 = blockIdx.x * 32;
    const int h  = blockIdx.y;
    const int b  = blockIdx.z;
    const int tid = threadIdx.x;

    // phase 1: coalesced read 64c x 32w (lanes along w)
    for (int i = tid; i < 2048; i += 256) {
        int c = i >> 5, wi = i & 31;
        ts[c][wi] = x[(((size_t)b * CC + c) * HH + h) * WW + w0 + wi];
    }
    __syncthreads();
    // GAP partial: one thread per channel sums its 32 w's
    if (tid < 64) {
        float s = 0.f;
        #pragma unroll 8
        for (int wi = 0; wi < 32; ++wi) s += ts[tid][wi];
        atomicAdd(&gap[b * CC + tid], s);
    }
    // phase 2: write transposed bf16 hi/lo (lanes along c -> coalesced)
    for (int i = tid; i < 2048; i += 256) {
        int c = i & 63, w = i >> 6;
        float v = ts[c][w];
        unsigned short hi = f2bf(v);
        unsigned short lo = f2bf(v - bf2f(hi));
        size_t off = (((size_t)(b * HH + h)) * WW + w0 + w) * CC + c;
        xt_hi[off] = hi;
        xt_lo[off] = lo;
    }
}

// ---------------------------------------------------------------------------
// Kernel B: routing MLP + BN + 4 attention heads. One block per batch sample.
// gap input holds raw sums -> normalize by 1/HWQ here.
// ---------------------------------------------------------------------------
__global__ __launch_bounds__(128) void mlp_kernel(
    const float* __restrict__ scale,
    const float* __restrict__ rw1, const float* __restrict__ rb1,
    const float* __restrict__ rw2, const float* __restrict__ rb2,
    const float* __restrict__ fc_w,
    const float* __restrict__ bn_gamma, const float* __restrict__ bn_beta,
    const float* __restrict__ bn_mean, const float* __restrict__ bn_var,
    const float* __restrict__ cfc_w, const float* __restrict__ cfc_b,
    const float* __restrict__ ffc_w, const float* __restrict__ ffc_b,
    const float* __restrict__ sfc_w, const float* __restrict__ sfc_b,
    const float* __restrict__ kfc_w, const float* __restrict__ kfc_b,
    const float* __restrict__ gap,
    float* __restrict__ ca, float* __restrict__ fa,
    float* __restrict__ sa, float* __restrict__ ka) {
    int b = blockIdx.x;
    int t = threadIdx.x;
    __shared__ float sin_[CC + 2];
    __shared__ float h1[2 * CC];
    __shared__ float h2[CC];
    __shared__ float vv[AA];
    __shared__ float kl[KK];

    if (t < 2) sin_[t] = 1.0f / scale[t];
    else if (t < CC + 2) sin_[t] = gap[b * CC + (t - 2)] * (1.0f / (float)HWQ);
    __syncthreads();

    {
        float a = rb1[t];
        const float* wr = rw1 + (size_t)t * (CC + 2);
        #pragma unroll 6
        for (int j = 0; j < CC + 2; ++j) a += sin_[j] * wr[j];
        h1[t] = fmaxf(a, 0.f);
    }
    __syncthreads();

    if (t < CC) {
        float a = rb2[t];
        const float* wr = rw2 + (size_t)t * (2 * CC);
        #pragma unroll 8
        for (int j = 0; j < 2 * CC; ++j) a += h1[j] * wr[j];
        h2[t] = fmaxf(a, 0.f);
    }
    __syncthreads();

    if (t < AA) {
        float a = 0.f;
        const float* wr = fc_w + (size_t)t * CC;
        #pragma unroll 8
        for (int j = 0; j < CC; ++j) a += h2[j] * wr[j];
        a = (a - bn_mean[t]) * rsqrtf(bn_var[t] + 1e-5f) * bn_gamma[t] + bn_beta[t];
        vv[t] = fmaxf(a, 0.f);
    }
    __syncthreads();

    if (t < CC) {
        float a = cfc_b[t];
        const float* wr = cfc_w + (size_t)t * AA;
        #pragma unroll
        for (int j = 0; j < AA; ++j) a += vv[j] * wr[j];
        ca[b * CC + t] = 1.f / (1.f + expf(-a));
        float f = ffc_b[t];
        const float* wf = ffc_w + (size_t)t * AA;
        #pragma unroll
        for (int j = 0; j < AA; ++j) f += vv[j] * wf[j];
        fa[b * CC + t] = 1.f / (1.f + expf(-f));
    }
    if (t < 9) {
        float a = sfc_b[t];
        const float* wr = sfc_w + (size_t)t * AA;
        #pragma unroll
        for (int j = 0; j < AA; ++j) a += vv[j] * wr[j];
        sa[b * 16 + t] = 1.f / (1.f + expf(-a));
    }
    if (t < KK) {
        float a = kfc_b[t];
        const float* wr = kfc_w + (size_t)t * AA;
        #pragma unroll
        for (int j = 0; j < AA; ++j) a += vv[j] * wr[j];
        kl[t] = a;
    }
    __syncthreads();
    if (t < KK) {
        float m = kl[0];
        #pragma unroll
        for (int j = 1; j < KK; ++j) m = fmaxf(m, kl[j]);
        float sum = 0.f;
        #pragma unroll
        for (int j = 0; j < KK; ++j) sum += expf(kl[j] - m);
        ka[b * KK + t] = expf(kl[t] - m) / sum;
    }
}

// ---------------------------------------------------------------------------
// Kernel C: aggregate expert weights (fold ca/fa/sa), split into bf16 hi/lo,
// and emit directly in MFMA A-fragment lane order:
//   lane = (o&15) | ((c_local>>3)<<4), elem j = c_local&7, ch = c>>5
// so the conv kernel's A-load is  base + lane*16B  (fully coalesced).
// ---------------------------------------------------------------------------
__global__ __launch_bounds__(256) void agg_frag_kernel(
    const float* __restrict__ weight,
    const float* __restrict__ ca, const float* __restrict__ fa,
    const float* __restrict__ sa, const float* __restrict__ ka,
    unsigned short* __restrict__ Ahi, unsigned short* __restrict__ Alo) {
    int e = blockIdx.x * 256 + threadIdx.x;   // < 16*64*64*9 = 589824
    int q  = e % 9;
    int t2 = e / 9;
    int c  = t2 & 63;
    int bo = t2 >> 6;
    int o  = bo & 63;
    int b  = bo >> 6;
    float s = 0.f;
    #pragma unroll
    for (int k = 0; k < KK; ++k)
        s += ka[b * KK + k] * weight[(((size_t)(k * OO + o)) * CC + c) * 9 + q];
    float val = s * sa[b * 16 + q] * ca[b * CC + c] * fa[b * CC + o];
    unsigned short hi = f2bf(val);
    unsigned short lo = f2bf(val - bf2f(hi));
    int mt = o >> 4;
    int lane = (o & 15) | (((c >> 3) & 3) << 4);
    int j = c & 7;
    int ch = c >> 5;
    size_t off = ((((size_t)(b * 9 + q) * 2 + ch) * 4 + mt) * 64 + lane) * 8 + j;
    Ahi[off] = hi;
    Alo[off] = lo;
}

// ---------------------------------------------------------------------------
// Kernel D: per-sample 3x3 conv via split-bf16 MFMA (implicit GEMM).
// M=64 (o), N=16 px per wave (1 row x 16 w), K=576 in 18 steps of 32
// (q-major, c-minor).  Block = 4 waves = 4 output rows x 16 w x 64 o.
// x tile (6 rows x 18 cols x 64 c, hi+lo) staged in LDS with XOR-swizzled
// c-granules so ds_read_b128 B-fragment reads are <=2-way banked (free).
// acc += Ahi*Bhi + Ahi*Blo + Alo*Bhi  (dropped Alo*Blo ~ 2^-16 relative).
// ---------------------------------------------------------------------------
__global__ __launch_bounds__(256) void conv_mfma_kernel(
    const unsigned short* __restrict__ xt_hi,
    const unsigned short* __restrict__ xt_lo,
    const unsigned short* __restrict__ Ahi,
    const unsigned short* __restrict__ Alo,
    float* __restrict__ out) {
    __shared__ __align__(16) unsigned short xs_hi[6 * 18 * 64];
    __shared__ __align__(16) unsigned short xs_lo[6 * 18 * 64];

    const int b  = blockIdx.z;
    const int h0 = blockIdx.y * 4;
    const int w0 = blockIdx.x * 16;
    const int tid  = threadIdx.x;
    const int wv   = tid >> 6;        // wave id = output row within tile
    const int lane = tid & 63;

    // ---- stage x tile: rows h0-1..h0+4, cols w0-1..w0+16, all 64 c ----
    for (int i = tid; i < 6 * 18 * 8; i += 256) {
        int g   = i & 7;
        int col = (i >> 3) % 18;
        int row = i / (8 * 18);
        int gh = h0 - 1 + row;
        int gw = w0 - 1 + col;
        uint4 vhi = {0u, 0u, 0u, 0u}, vlo = {0u, 0u, 0u, 0u};
        if ((unsigned)gh < (unsigned)HH && (unsigned)gw < (unsigned)WW) {
            size_t off = (((size_t)(b * HH + gh)) * WW + gw) * CC + g * 8;
            vhi = *(const uint4*)(xt_hi + off);
            vlo = *(const uint4*)(xt_lo + off);
        }
        int lidx = (row * 18 + col) * 64 + ((g ^ (col & 7)) << 3);
        *(uint4*)(&xs_hi[lidx]) = vhi;
        *(uint4*)(&xs_lo[lidx]) = vlo;
    }
    __syncthreads();

    fx4 z = {0.f, 0.f, 0.f, 0.f};
    fx4 acc[4] = {z, z, z, z};

    const int lr  = lane & 15;        // A row (o within 16) / B col (px)
    const int l4  = lane >> 4;        // k-subblock 0..3

    #pragma unroll
    for (int q = 0; q < 9; ++q) {
        const int kh = q / 3, kw = q % 3;
        const int row = wv + kh;
        const int col = lr + kw;
        const int lbase = (row * 18 + col) * 64;
        #pragma unroll
        for (int ch = 0; ch < 2; ++ch) {
            const int g = ch * 4 + l4;
            const int lidx = lbase + ((g ^ (col & 7)) << 3);
            sh8 bhi = *(const sh8*)(&xs_hi[lidx]);
            sh8 blo = *(const sh8*)(&xs_lo[lidx]);
            const size_t abase =
                ((size_t)((b * 9 + q) * 2 + ch) * 4) * 512 + lane * 8;
            #pragma unroll
            for (int mt = 0; mt < 4; ++mt) {
                sh8 a_hi = *(const sh8*)(Ahi + abase + mt * 512);
                sh8 a_lo = *(const sh8*)(Alo + abase + mt * 512);
                acc[mt] = __builtin_amdgcn_mfma_f32_16x16x32_bf16(
                    a_hi, bhi, acc[mt], 0, 0, 0);
                acc[mt] = __builtin_amdgcn_mfma_f32_16x16x32_bf16(
                    a_hi, blo, acc[mt], 0, 0, 0);
                acc[mt] = __builtin_amdgcn_mfma_f32_16x16x32_bf16(
                    a_lo, bhi, acc[mt], 0, 0, 0);
            }
        }
    }

    // ---- epilogue: D layout col=lane&15 (px), row=(lane>>4)*4+reg (o) ----
    const int dw = lr;
    const int osub = l4 * 4;
    const int hrow = h0 + wv;
    #pragma unroll
    for (int mt = 0; mt < 4; ++mt) {
        #pragma unroll
        for (int jj = 0; jj < 4; ++jj) {
            int o = mt * 16 + osub + jj;
            out[((size_t)(b * OO + o)) * HWQ + hrow * WW + w0 + dw] = acc[mt][jj];
        }
    }
}

// ---------------------------------------------------------------------------
extern "C" void kernel_launch(void* const* d_in, const int* in_sizes, int n_in,
                              void* d_out, int out_size, void* d_ws, size_t ws_size,
                              hipStream_t stream) {
    const float* x        = (const float*)d_in[0];
    const float* scale    = (const float*)d_in[1];
    const float* rw1      = (const float*)d_in[2];
    const float* rb1      = (const float*)d_in[3];
    const float* rw2      = (const float*)d_in[4];
    const float* rb2      = (const float*)d_in[5];
    const float* fc_w     = (const float*)d_in[6];
    const float* bn_gamma = (const float*)d_in[7];
    const float* bn_beta  = (const float*)d_in[8];
    const float* bn_mean  = (const float*)d_in[9];
    const float* bn_var   = (const float*)d_in[10];
    const float* cfc_w    = (const float*)d_in[11];
    const float* cfc_b    = (const float*)d_in[12];
    const float* ffc_w    = (const float*)d_in[13];
    const float* ffc_b    = (const float*)d_in[14];
    const float* sfc_w    = (const float*)d_in[15];
    const float* sfc_b    = (const float*)d_in[16];
    const float* kfc_w    = (const float*)d_in[17];
    const float* kfc_b    = (const float*)d_in[18];
    const float* weight   = (const float*)d_in[19];

    // workspace layout (bytes):
    //   [0)        gap      1024 f32   (4 KB used of 16 KB slot)
    //   [16384)    Ahi      589824 bf16 (1179648 B)
    //   [1196032)  Alo      589824 bf16
    //   [2375680)  xt_hi    26214400 bf16 (52428800 B)
    //   [54804480) xt_lo    26214400 bf16
    //   total = 107233280 B
    const size_t WS_NEEDED = 107233280u;
    if (ws_size < WS_NEEDED) return;  // fail cleanly (poisoned d_out), don't crash

    char* wsb = (char*)d_ws;
    float* gap = (float*)(wsb + 0);
    float* ca  = (float*)(wsb + 4096);
    float* fa  = (float*)(wsb + 8192);
    float* sa  = (float*)(wsb + 12288);
    float* ka  = (float*)(wsb + 13312);
    unsigned short* Ahi  = (unsigned short*)(wsb + 16384);
    unsigned short* Alo  = (unsigned short*)(wsb + 1196032);
    unsigned short* xthi = (unsigned short*)(wsb + 2375680);
    unsigned short* xtlo = (unsigned short*)(wsb + 54804480);

    hipMemsetAsync(gap, 0, 1024 * sizeof(float), stream);
    trans_gap_kernel<<<dim3(5, 160, 16), dim3(256), 0, stream>>>(
        x, xthi, xtlo, gap);
    mlp_kernel<<<dim3(BB), dim3(128), 0, stream>>>(
        scale, rw1, rb1, rw2, rb2, fc_w, bn_gamma, bn_beta, bn_mean, bn_var,
        cfc_w, cfc_b, ffc_w, ffc_b, sfc_w, sfc_b, kfc_w, kfc_b,
        gap, ca, fa, sa, ka);
    agg_frag_kernel<<<dim3(589824 / 256), dim3(256), 0, stream>>>(
        weight, ca, fa, sa, ka, Ahi, Alo);
    conv_mfma_kernel<<<dim3(10, 40, 16), dim3(256), 0, stream>>>(
        xthi, xtlo, Ahi, Alo, (float*)d_out);
}

// Round 6
// 340.287 us; speedup vs baseline: 1.8464x; 1.1835x over previous
//
#include <hip/hip_runtime.h>
#include <math.h>

// Problem constants
#define BB 16
#define CC 64
#define HH 160
#define WW 160
#define KK 8
#define OO 64
#define AA 16
#define HWQ (HH * WW)          // 25600

typedef __attribute__((ext_vector_type(8))) short sh8;
typedef __attribute__((ext_vector_type(4))) float fx4;

__device__ inline unsigned short f2bf(float f) {
    unsigned int u = __float_as_uint(f);
    return (unsigned short)((u + 0x7FFFu + ((u >> 16) & 1u)) >> 16);
}
__device__ inline float bf2f(unsigned short h) {
    return __uint_as_float(((unsigned int)h) << 16);
}

// ---------------------------------------------------------------------------
// Kernel A: transpose x [b][c][h][w] fp32 -> xt_hi/xt_lo [b][h][w][c] bf16
// (split precision: x = hi + lo). Vectorized: float4 global loads, short8
// global stores. GAP partials written per (b, h-half) row (no atomics);
// reduced later inside mlp_kernel. One block per (b, h, half of w).
// ---------------------------------------------------------------------------
__global__ __launch_bounds__(256) void trans_kernel(
    const float* __restrict__ x,
    unsigned short* __restrict__ xt_hi, unsigned short* __restrict__ xt_lo,
    float* __restrict__ pg) {
    __shared__ float ts[64][84];     // 21.5 KB, row stride 336B (16B-aligned)
    const int half = blockIdx.x;     // 0..1
    const int h    = blockIdx.y;     // 0..159
    const int b    = blockIdx.z;
    const int w0   = half * 80;
    const int tid  = threadIdx.x;

    // phase 1: 64c x 80w as float4 (16B/lane, ~320B segments)
    for (int i = tid; i < 1280; i += 256) {
        int c  = i / 20;
        int wq = i % 20;
        float4 v = *(const float4*)(
            x + (((size_t)(b * CC + c)) * HH + h) * WW + w0 + wq * 4);
        *(float4*)(&ts[c][wq * 4]) = v;
    }
    __syncthreads();

    // GAP partial: thread c sums its 80 w's -> pg[(b*320 + h*2+half)*64 + c]
    if (tid < 64) {
        float s = 0.f;
        #pragma unroll 10
        for (int w = 0; w < 80; ++w) s += ts[tid][w];
        pg[((size_t)b * 320 + h * 2 + half) * 64 + tid] = s;
    }

    // phase 2: pack 8 c's per store -> 1KB/wave contiguous stores
    for (int i = tid; i < 640; i += 256) {
        int g = i & 7;            // c granule
        int w = i >> 3;           // 0..79
        sh8 vh, vl;
        #pragma unroll
        for (int e = 0; e < 8; ++e) {
            float v = ts[g * 8 + e][w];
            unsigned short hh = f2bf(v);
            vh[e] = (short)hh;
            vl[e] = (short)f2bf(v - bf2f(hh));
        }
        size_t off = (((size_t)(b * HH + h)) * WW + w0 + w) * CC + g * 8;
        *(sh8*)(xt_hi + off) = vh;
        *(sh8*)(xt_lo + off) = vl;
    }
}

// ---------------------------------------------------------------------------
// Kernel B: GAP reduction + routing MLP + BN + 4 attention heads.
// One block per batch sample.
// ---------------------------------------------------------------------------
__global__ __launch_bounds__(128) void mlp_kernel(
    const float* __restrict__ scale,
    const float* __restrict__ rw1, const float* __restrict__ rb1,
    const float* __restrict__ rw2, const float* __restrict__ rb2,
    const float* __restrict__ fc_w,
    const float* __restrict__ bn_gamma, const float* __restrict__ bn_beta,
    const float* __restrict__ bn_mean, const float* __restrict__ bn_var,
    const float* __restrict__ cfc_w, const float* __restrict__ cfc_b,
    const float* __restrict__ ffc_w, const float* __restrict__ ffc_b,
    const float* __restrict__ sfc_w, const float* __restrict__ sfc_b,
    const float* __restrict__ kfc_w, const float* __restrict__ kfc_b,
    const float* __restrict__ pg,
    float* __restrict__ ca, float* __restrict__ fa,
    float* __restrict__ sa, float* __restrict__ ka) {
    int b = blockIdx.x;
    int t = threadIdx.x;
    __shared__ float sin_[CC + 2];
    __shared__ float h1[2 * CC];
    __shared__ float h2[CC];
    __shared__ float vv[AA];
    __shared__ float kl[KK];

    if (t < 2) sin_[t] = 1.0f / scale[t];
    // GAP: reduce 320 partials per channel (coalesced 256B rows)
    if (t < CC) {
        float s = 0.f;
        for (int h2v = 0; h2v < 320; ++h2v)
            s += pg[((size_t)b * 320 + h2v) * 64 + t];
        sin_[2 + t] = s * (1.0f / (float)HWQ);
    }
    __syncthreads();

    {
        float a = rb1[t];
        const float* wr = rw1 + (size_t)t * (CC + 2);
        #pragma unroll 6
        for (int j = 0; j < CC + 2; ++j) a += sin_[j] * wr[j];
        h1[t] = fmaxf(a, 0.f);
    }
    __syncthreads();

    if (t < CC) {
        float a = rb2[t];
        const float* wr = rw2 + (size_t)t * (2 * CC);
        #pragma unroll 8
        for (int j = 0; j < 2 * CC; ++j) a += h1[j] * wr[j];
        h2[t] = fmaxf(a, 0.f);
    }
    __syncthreads();

    if (t < AA) {
        float a = 0.f;
        const float* wr = fc_w + (size_t)t * CC;
        #pragma unroll 8
        for (int j = 0; j < CC; ++j) a += h2[j] * wr[j];
        a = (a - bn_mean[t]) * rsqrtf(bn_var[t] + 1e-5f) * bn_gamma[t] + bn_beta[t];
        vv[t] = fmaxf(a, 0.f);
    }
    __syncthreads();

    if (t < CC) {
        float a = cfc_b[t];
        const float* wr = cfc_w + (size_t)t * AA;
        #pragma unroll
        for (int j = 0; j < AA; ++j) a += vv[j] * wr[j];
        ca[b * CC + t] = 1.f / (1.f + expf(-a));
        float f = ffc_b[t];
        const float* wf = ffc_w + (size_t)t * AA;
        #pragma unroll
        for (int j = 0; j < AA; ++j) f += vv[j] * wf[j];
        fa[b * CC + t] = 1.f / (1.f + expf(-f));
    }
    if (t < 9) {
        float a = sfc_b[t];
        const float* wr = sfc_w + (size_t)t * AA;
        #pragma unroll
        for (int j = 0; j < AA; ++j) a += vv[j] * wr[j];
        sa[b * 16 + t] = 1.f / (1.f + expf(-a));
    }
    if (t < KK) {
        float a = kfc_b[t];
        const float* wr = kfc_w + (size_t)t * AA;
        #pragma unroll
        for (int j = 0; j < AA; ++j) a += vv[j] * wr[j];
        kl[t] = a;
    }
    __syncthreads();
    if (t < KK) {
        float m = kl[0];
        #pragma unroll
        for (int j = 1; j < KK; ++j) m = fmaxf(m, kl[j]);
        float sum = 0.f;
        #pragma unroll
        for (int j = 0; j < KK; ++j) sum += expf(kl[j] - m);
        ka[b * KK + t] = expf(kl[t] - m) / sum;
    }
}

// ---------------------------------------------------------------------------
// Kernel C: aggregate expert weights (fold ca/fa/sa), split into bf16 hi/lo,
// and emit directly in MFMA A-fragment lane order:
//   lane = (o&15) | ((c_local>>3)<<4), elem j = c_local&7, ch = c>>5
// so the conv kernel's A-load is  base + lane*16B  (fully coalesced).
// ---------------------------------------------------------------------------
__global__ __launch_bounds__(256) void agg_frag_kernel(
    const float* __restrict__ weight,
    const float* __restrict__ ca, const float* __restrict__ fa,
    const float* __restrict__ sa, const float* __restrict__ ka,
    unsigned short* __restrict__ Ahi, unsigned short* __restrict__ Alo) {
    int e = blockIdx.x * 256 + threadIdx.x;   // < 16*64*64*9 = 589824
    int q  = e % 9;
    int t2 = e / 9;
    int c  = t2 & 63;
    int bo = t2 >> 6;
    int o  = bo & 63;
    int b  = bo >> 6;
    float s = 0.f;
    #pragma unroll
    for (int k = 0; k < KK; ++k)
        s += ka[b * KK + k] * weight[(((size_t)(k * OO + o)) * CC + c) * 9 + q];
    float val = s * sa[b * 16 + q] * ca[b * CC + c] * fa[b * CC + o];
    unsigned short hi = f2bf(val);
    unsigned short lo = f2bf(val - bf2f(hi));
    int mt = o >> 4;
    int lane = (o & 15) | (((c >> 3) & 3) << 4);
    int j = c & 7;
    int ch = c >> 5;
    size_t off = ((((size_t)(b * 9 + q) * 2 + ch) * 4 + mt) * 64 + lane) * 8 + j;
    Ahi[off] = hi;
    Alo[off] = lo;
}

// ---------------------------------------------------------------------------
// Kernel D: per-sample 3x3 conv via split-bf16 MFMA (implicit GEMM).
// M=64 (o), N=32 px per wave (2 rows x 16 w), K=576 in 18 steps of 32
// (q-major, c-minor).  Block = 4 waves = 8 output rows x 16 w x 64 o.
// x tile (10 rows x 18 cols x 64 c, hi+lo) staged in LDS, XOR-swizzled
// c-granules -> <=2-way banked ds_read_b128 (free).
// acc += Ahi*Bhi + Ahi*Blo + Alo*Bhi  (dropped Alo*Blo ~ 2^-16 relative).
// ---------------------------------------------------------------------------
__global__ __launch_bounds__(256) void conv_mfma_kernel(
    const unsigned short* __restrict__ xt_hi,
    const unsigned short* __restrict__ xt_lo,
    const unsigned short* __restrict__ Ahi,
    const unsigned short* __restrict__ Alo,
    float* __restrict__ out) {
    __shared__ __align__(16) unsigned short xs_hi[10 * 18 * 64];
    __shared__ __align__(16) unsigned short xs_lo[10 * 18 * 64];

    const int b  = blockIdx.z;
    const int h0 = blockIdx.y * 8;
    const int w0 = blockIdx.x * 16;
    const int tid  = threadIdx.x;
    const int wv   = tid >> 6;        // wave id -> rows 2wv, 2wv+1
    const int lane = tid & 63;

    // ---- stage x tile: rows h0-1..h0+8, cols w0-1..w0+16, all 64 c ----
    for (int i = tid; i < 10 * 18 * 8; i += 256) {
        int g   = i & 7;
        int col = (i >> 3) % 18;
        int row = i / 144;
        int gh = h0 - 1 + row;
        int gw = w0 - 1 + col;
        uint4 vhi = {0u, 0u, 0u, 0u}, vlo = {0u, 0u, 0u, 0u};
        if ((unsigned)gh < (unsigned)HH && (unsigned)gw < (unsigned)WW) {
            size_t off = (((size_t)(b * HH + gh)) * WW + gw) * CC + g * 8;
            vhi = *(const uint4*)(xt_hi + off);
            vlo = *(const uint4*)(xt_lo + off);
        }
        int lidx = (row * 18 + col) * 64 + ((g ^ (col & 7)) << 3);
        *(uint4*)(&xs_hi[lidx]) = vhi;
        *(uint4*)(&xs_lo[lidx]) = vlo;
    }
    __syncthreads();

    fx4 z = {0.f, 0.f, 0.f, 0.f};
    fx4 acc[2][4] = {{z, z, z, z}, {z, z, z, z}};

    const int lr = lane & 15;         // A row (o within 16) / B col (px)
    const int l4 = lane >> 4;         // k-subblock 0..3

    #pragma unroll
    for (int q = 0; q < 9; ++q) {
        const int kh = q / 3, kw = q % 3;
        const int col = lr + kw;
        #pragma unroll
        for (int ch = 0; ch < 2; ++ch) {
            const int g  = ch * 4 + l4;
            const int cg = (g ^ (col & 7)) << 3;
            sh8 bhi[2], blo[2];
            #pragma unroll
            for (int nr = 0; nr < 2; ++nr) {
                const int row  = wv * 2 + nr + kh;
                const int lidx = (row * 18 + col) * 64 + cg;
                bhi[nr] = *(const sh8*)(&xs_hi[lidx]);
                blo[nr] = *(const sh8*)(&xs_lo[lidx]);
            }
            const size_t abase =
                ((size_t)((b * 9 + q) * 2 + ch)) * 2048 + lane * 8;
            #pragma unroll
            for (int mt = 0; mt < 4; ++mt) {
                sh8 a_hi = *(const sh8*)(Ahi + abase + mt * 512);
                sh8 a_lo = *(const sh8*)(Alo + abase + mt * 512);
                #pragma unroll
                for (int nr = 0; nr < 2; ++nr) {
                    acc[nr][mt] = __builtin_amdgcn_mfma_f32_16x16x32_bf16(
                        a_hi, bhi[nr], acc[nr][mt], 0, 0, 0);
                    acc[nr][mt] = __builtin_amdgcn_mfma_f32_16x16x32_bf16(
                        a_hi, blo[nr], acc[nr][mt], 0, 0, 0);
                    acc[nr][mt] = __builtin_amdgcn_mfma_f32_16x16x32_bf16(
                        a_lo, bhi[nr], acc[nr][mt], 0, 0, 0);
                }
            }
        }
    }

    // ---- epilogue: D layout col=lane&15 (px), row=(lane>>4)*4+reg (o) ----
    #pragma unroll
    for (int nr = 0; nr < 2; ++nr) {
        const int hrow = h0 + wv * 2 + nr;
        #pragma unroll
        for (int mt = 0; mt < 4; ++mt) {
            #pragma unroll
            for (int jj = 0; jj < 4; ++jj) {
                int o = mt * 16 + l4 * 4 + jj;
                out[((size_t)(b * OO + o)) * HWQ + hrow * WW + w0 + lr] =
                    acc[nr][mt][jj];
            }
        }
    }
}

// ---------------------------------------------------------------------------
extern "C" void kernel_launch(void* const* d_in, const int* in_sizes, int n_in,
                              void* d_out, int out_size, void* d_ws, size_t ws_size,
                              hipStream_t stream) {
    const float* x        = (const float*)d_in[0];
    const float* scale    = (const float*)d_in[1];
    const float* rw1      = (const float*)d_in[2];
    const float* rb1      = (const float*)d_in[3];
    const float* rw2      = (const float*)d_in[4];
    const float* rb2      = (const float*)d_in[5];
    const float* fc_w     = (const float*)d_in[6];
    const float* bn_gamma = (const float*)d_in[7];
    const float* bn_beta  = (const float*)d_in[8];
    const float* bn_mean  = (const float*)d_in[9];
    const float* bn_var   = (const float*)d_in[10];
    const float* cfc_w    = (const float*)d_in[11];
    const float* cfc_b    = (const float*)d_in[12];
    const float* ffc_w    = (const float*)d_in[13];
    const float* ffc_b    = (const float*)d_in[14];
    const float* sfc_w    = (const float*)d_in[15];
    const float* sfc_b    = (const float*)d_in[16];
    const float* kfc_w    = (const float*)d_in[17];
    const float* kfc_b    = (const float*)d_in[18];
    const float* weight   = (const float*)d_in[19];

    // workspace layout (bytes):
    //   [0)        ca/fa/sa/ka small vectors (16 KB)
    //   [16384)    A-fragment region: Ahi [16384,1196032), Alo [1196032,2375680)
    //              pg (GAP partials, 16*320*64 f32 = 1310720 B) ALIASES
    //              [16384,1327104): written by trans, read by mlp, then
    //              clobbered by agg (stream-ordered -> safe).
    //   [2375680)  xt_hi 26214400 bf16 (52428800 B)
    //   [54804480) xt_lo 26214400 bf16
    //   total = 107233280 B (proven sufficient in round 5)
    const size_t WS_NEEDED = 107233280u;
    if (ws_size < WS_NEEDED) return;  // fail cleanly, don't crash

    char* wsb = (char*)d_ws;
    float* ca  = (float*)(wsb + 0);
    float* fa  = (float*)(wsb + 4096);
    float* sa  = (float*)(wsb + 8192);
    float* ka  = (float*)(wsb + 12288);
    float* pg  = (float*)(wsb + 16384);
    unsigned short* Ahi  = (unsigned short*)(wsb + 16384);
    unsigned short* Alo  = (unsigned short*)(wsb + 1196032);
    unsigned short* xthi = (unsigned short*)(wsb + 2375680);
    unsigned short* xtlo = (unsigned short*)(wsb + 54804480);

    trans_kernel<<<dim3(2, 160, 16), dim3(256), 0, stream>>>(
        x, xthi, xtlo, pg);
    mlp_kernel<<<dim3(BB), dim3(128), 0, stream>>>(
        scale, rw1, rb1, rw2, rb2, fc_w, bn_gamma, bn_beta, bn_mean, bn_var,
        cfc_w, cfc_b, ffc_w, ffc_b, sfc_w, sfc_b, kfc_w, kfc_b,
        pg, ca, fa, sa, ka);
    agg_frag_kernel<<<dim3(589824 / 256), dim3(256), 0, stream>>>(
        weight, ca, fa, sa, ka, Ahi, Alo);
    conv_mfma_kernel<<<dim3(10, 20, 16), dim3(256), 0, stream>>>(
        xthi, xtlo, Ahi, Alo, (float*)d_out);
}